// Round 2
// baseline (95.264 us; speedup 1.0000x reference)
//
#include <hip/hip_runtime.h>
#include <stdint.h>

typedef __attribute__((ext_vector_type(8))) short bf16x8;
typedef __attribute__((ext_vector_type(4))) float f32x4;
typedef unsigned short u16;

constexpr int NN = 2048, NF = 256;

__device__ inline u16 f2bf(float f) {
  uint32_t u = __builtin_bit_cast(uint32_t, f);
  uint32_t r = (u + 0x7FFFu + ((u >> 16) & 1u)) >> 16;
  return (u16)r;
}

__device__ inline void gload_lds16(const void* g, void* l) {
  __builtin_amdgcn_global_load_lds(
      (const __attribute__((address_space(1))) uint32_t*)g,
      (__attribute__((address_space(3))) uint32_t*)l,
      16, 0, 0);
}

// ---------------- K1: d[b,i] = rsqrt(1 + sum_j adj[b,i,j]) ----------------
__global__ __launch_bounds__(256) void k_rowsum(const float* __restrict__ adj,
                                                float* __restrict__ d) {
  int row = blockIdx.x;  // b*2048 + i
  const float4* p = (const float4*)(adj + (size_t)row * NN);
  float s = 0.f;
#pragma unroll
  for (int c = 0; c < 2; ++c) {
    float4 v = p[threadIdx.x + 256 * c];
    s += v.x + v.y + v.z + v.w;
  }
#pragma unroll
  for (int off = 32; off > 0; off >>= 1) s += __shfl_down(s, off, 64);
  __shared__ float red[4];
  int lane = threadIdx.x & 63, w = threadIdx.x >> 6;
  if (lane == 0) red[w] = s;
  __syncthreads();
  if (threadIdx.x == 0) {
    float t = red[0] + red[1] + red[2] + red[3] + 1.0f;
    d[row] = 1.0f / sqrtf(t);
  }
}

// ---------------- Wconv: W fp32 -> bf16 ([o][f] kept) -----------------------
__global__ __launch_bounds__(256) void k_wconv(const float* __restrict__ W,
                                               u16* __restrict__ Wb) {
  int i = blockIdx.x * 256 + threadIdx.x;
  float4 v = ((const float4*)W)[i];
  ushort4 o;
  o.x = f2bf(v.x); o.y = f2bf(v.y); o.z = f2bf(v.z); o.w = f2bf(v.w);
  *(ushort4*)(Wb + (size_t)i * 4) = o;
}

// ---------------- K2: XpT[b,f,j'] = bf16(d_j * X[b,j,f]), j' XOR-swizzled ---
// Swizzle: within each 32-j block, 16B-chunk index XORed with ((f>>1)&3)
// so that linear gload_lds staging lands bank-conflict-free for frag reads.
__global__ __launch_bounds__(256) void k_xprep(const float* __restrict__ X,
                                               const float* __restrict__ d,
                                               u16* __restrict__ XpT) {
  int jt = blockIdx.x, ft = blockIdx.y, b = blockIdx.z;
  int j0 = jt * 64, f0 = ft * 64;
  __shared__ u16 T[64][66];
  int t = threadIdx.x;
#pragma unroll
  for (int s = 0; s < 4; ++s) {
    int q = s * 256 + t;
    int r = q >> 4, c4 = q & 15;
    int j = j0 + r;
    float dv = d[b * NN + j];
    float4 v = *(const float4*)(X + ((size_t)(b * NN + j)) * NF + f0 + c4 * 4);
    T[r][c4 * 4 + 0] = f2bf(v.x * dv);
    T[r][c4 * 4 + 1] = f2bf(v.y * dv);
    T[r][c4 * 4 + 2] = f2bf(v.z * dv);
    T[r][c4 * 4 + 3] = f2bf(v.w * dv);
  }
  __syncthreads();
#pragma unroll
  for (int s = 0; s < 4; ++s) {
    int q = s * 256 + t;
    int fr = q >> 4, c4 = q & 15;
    int f = f0 + fr;
    int swz = (f >> 1) & 3;
    int joff = (c4 * 4) ^ (swz << 3);  // XOR hits only bits 3..4
    ushort4 o;
    o.x = T[c4 * 4 + 0][fr]; o.y = T[c4 * 4 + 1][fr];
    o.z = T[c4 * 4 + 2][fr]; o.w = T[c4 * 4 + 3][fr];
    *(ushort4*)(XpT + ((size_t)(b * NF + f)) * NN + j0 + joff) = o;
  }
}

// ---------------- Fused: H = d_i*(adj@Xp) + d_i^2*X ; out = relu(H@W^T + b) -
// BM=64, BN=256(all F), BK=32, 512 threads (8 waves, 2x4), dbuf LDS pipeline.
__global__ __launch_bounds__(512, 2) void k_fused(
    const float* __restrict__ adj, const u16* __restrict__ XpT,
    const float* __restrict__ X, const float* __restrict__ dsc,
    const u16* __restrict__ Wb, const float* __restrict__ bias,
    float* __restrict__ out) {
  // batch<->XCD remap: blocks with same b land on same XCD (1MB XpT L2-resident)
  int flat = blockIdx.x;
  int b = flat & 7, mt = flat >> 3;
  int i0 = mt * 64;

  __shared__ __align__(16) char smem[40960];
  u16* As0 = (u16*)smem;
  u16* As1 = (u16*)(smem + 4096);
  u16* Bs0 = (u16*)(smem + 8192);
  u16* Bs1 = (u16*)(smem + 24576);
  u16* Hs = (u16*)smem;  // aliased after the K loop

  int t = threadIdx.x;
  int lane = t & 63, w = t >> 6;
  int l15 = lane & 15, l4 = lane >> 4;
  int wr = w >> 2, wc = w & 3;

  const float* adjb = adj + ((size_t)b * NN + i0) * NN;
  const u16* XpTb = XpT + (size_t)b * NF * NN;

  // A staging: 64x32 fp32 -> bf16; thread t handles row ar, float4 col ac4
  int ar = t >> 3, ac4 = t & 7;
  const float* a_row = adjb + (size_t)ar * NN + ac4 * 4;
  int a_chunk = (ac4 >> 1) ^ ((ar >> 1) & 3);            // 16B-chunk swizzle
  int a_wr_off = ar * 64 + a_chunk * 16 + (ac4 & 1) * 8; // byte offset

  f32x4 acc[2][4] = {};
  float4 araw;

  // ---- prologue: B(0)->Bs0, A(0)->regs, B(1)->Bs1 ----
#pragma unroll
  for (int c = 0; c < 2; ++c) {
    int q = c * 512 + t;
    gload_lds16(XpTb + (size_t)(q >> 2) * NN + (q & 3) * 8,
                (char*)Bs0 + (size_t)(c * 512 + w * 64) * 16);
  }
  __builtin_amdgcn_sched_barrier(0);
  araw = *(const float4*)(a_row);
  __builtin_amdgcn_sched_barrier(0);
#pragma unroll
  for (int c = 0; c < 2; ++c) {
    int q = c * 512 + t;
    gload_lds16(XpTb + (size_t)(q >> 2) * NN + 32 + (q & 3) * 8,
                (char*)Bs1 + (size_t)(c * 512 + w * 64) * 16);
  }
  __builtin_amdgcn_sched_barrier(0);
  asm volatile("s_waitcnt vmcnt(2)" ::: "memory");  // A(0), B(0) done
  {
    ushort4 o;
    o.x = f2bf(araw.x); o.y = f2bf(araw.y);
    o.z = f2bf(araw.z); o.w = f2bf(araw.w);
    *(ushort4*)((char*)As0 + a_wr_off) = o;
  }
  araw = *(const float4*)(a_row + 32);  // A(1)
  asm volatile("s_waitcnt lgkmcnt(0)" ::: "memory");
  __builtin_amdgcn_sched_barrier(0);
  __builtin_amdgcn_s_barrier();

  // ---- main K loop: 64 iters of BK=32 ----
  for (int k = 0; k < 64; ++k) {
    u16* Ac = (k & 1) ? As1 : As0;
    u16* An = (k & 1) ? As0 : As1;
    u16* Bc = (k & 1) ? Bs1 : Bs0;

    bf16x8 af[2], bfr[4];
#pragma unroll
    for (int mi = 0; mi < 2; ++mi) {
      int r = wr * 32 + mi * 16 + l15;
      af[mi] = *(const bf16x8*)((char*)Ac + r * 64 + ((l4 ^ ((r >> 1) & 3)) << 4));
    }
#pragma unroll
    for (int ni = 0; ni < 4; ++ni) {
      int n = wc * 64 + ni * 16 + l15;
      bfr[ni] = *(const bf16x8*)((char*)Bc + n * 64 + ((l4 ^ ((n >> 1) & 3)) << 4));
    }
    asm volatile("s_waitcnt lgkmcnt(0)" ::: "memory");
    __builtin_amdgcn_sched_barrier(0);
    __builtin_amdgcn_s_barrier();  // all waves done reading [cur]

    if (k < 62) {  // refill Bs[cur] with B(k+2)
      int k2 = (k + 2) * 32;
#pragma unroll
      for (int c = 0; c < 2; ++c) {
        int q = c * 512 + t;
        gload_lds16(XpTb + (size_t)(q >> 2) * NN + k2 + (q & 3) * 8,
                    (char*)Bc + (size_t)(c * 512 + w * 64) * 16);
      }
      __builtin_amdgcn_sched_barrier(0);
    }

    __builtin_amdgcn_s_setprio(1);
#pragma unroll
    for (int mi = 0; mi < 2; ++mi)
#pragma unroll
      for (int ni = 0; ni < 4; ++ni)
        acc[mi][ni] = __builtin_amdgcn_mfma_f32_16x16x32_bf16(af[mi], bfr[ni],
                                                              acc[mi][ni], 0, 0, 0);
    __builtin_amdgcn_s_setprio(0);

    if (k < 63) {
      if (k < 62) { asm volatile("s_waitcnt vmcnt(3)" ::: "memory"); }
      else        { asm volatile("s_waitcnt vmcnt(0)" ::: "memory"); }
      __builtin_amdgcn_sched_barrier(0);
      ushort4 o;
      o.x = f2bf(araw.x); o.y = f2bf(araw.y);
      o.z = f2bf(araw.z); o.w = f2bf(araw.w);
      *(ushort4*)((char*)An + a_wr_off) = o;
      if (k < 62) araw = *(const float4*)(a_row + (k + 2) * 32);
    }
    asm volatile("s_waitcnt lgkmcnt(0)" ::: "memory");
    __builtin_amdgcn_sched_barrier(0);
    __builtin_amdgcn_s_barrier();  // As[nxt] visible for next iter
  }

  // ---- epilogue 1: H tile -> LDS (bf16, stride 264 to dodge conflicts) ----
  const float* db = dsc + b * NN;
  const float* Xb = X + ((size_t)b * NN + i0) * NF;
#pragma unroll
  for (int mi = 0; mi < 2; ++mi) {
#pragma unroll
    for (int qq = 0; qq < 4; ++qq) {
      int il = wr * 32 + mi * 16 + l4 * 4 + qq;
      float dv = db[i0 + il];
      float dv2 = dv * dv;
#pragma unroll
      for (int ni = 0; ni < 4; ++ni) {
        int f = wc * 64 + ni * 16 + l15;
        float hv = dv * acc[mi][ni][qq] + dv2 * Xb[(size_t)il * NF + f];
        Hs[il * 264 + f] = f2bf(hv);
      }
    }
  }
  asm volatile("s_waitcnt lgkmcnt(0)" ::: "memory");
  __builtin_amdgcn_s_barrier();

  // ---- epilogue 2: out = relu(H @ W^T + bias), W frags from L2 ----
  f32x4 acc2[2][4] = {};
  for (int kk = 0; kk < 256; kk += 32) {
    bf16x8 a2[2], b2[4];
#pragma unroll
    for (int mi = 0; mi < 2; ++mi) {
      int r = wr * 32 + mi * 16 + l15;
      a2[mi] = *(const bf16x8*)&Hs[r * 264 + kk + l4 * 8];
    }
#pragma unroll
    for (int ni = 0; ni < 4; ++ni) {
      int o = wc * 64 + ni * 16 + l15;
      b2[ni] = *(const bf16x8*)&Wb[(size_t)o * 256 + kk + l4 * 8];
    }
#pragma unroll
    for (int mi = 0; mi < 2; ++mi)
#pragma unroll
      for (int ni = 0; ni < 4; ++ni)
        acc2[mi][ni] = __builtin_amdgcn_mfma_f32_16x16x32_bf16(a2[mi], b2[ni],
                                                               acc2[mi][ni], 0, 0, 0);
  }

  float* outb = out + ((size_t)b * NN + i0) * NF;
#pragma unroll
  for (int mi = 0; mi < 2; ++mi) {
#pragma unroll
    for (int qq = 0; qq < 4; ++qq) {
      int il = wr * 32 + mi * 16 + l4 * 4 + qq;
#pragma unroll
      for (int ni = 0; ni < 4; ++ni) {
        int o = wc * 64 + ni * 16 + l15;
        float v = acc2[mi][ni][qq] + bias[o];
        outb[(size_t)il * NF + o] = fmaxf(v, 0.f);
      }
    }
  }
}

extern "C" void kernel_launch(void* const* d_in, const int* in_sizes, int n_in,
                              void* d_out, int out_size, void* d_ws, size_t ws_size,
                              hipStream_t stream) {
  const float* X    = (const float*)d_in[0];
  const float* adj  = (const float*)d_in[1];
  const float* W    = (const float*)d_in[2];
  const float* bias = (const float*)d_in[3];
  float* out = (float*)d_out;

  char* ws = (char*)d_ws;
  float* dsc = (float*)(ws);                 // 64 KB
  u16*   Wb  = (u16*)(ws + 65536);           // 128 KB
  u16*   XpT = (u16*)(ws + 262144);          // 8 MB

  k_rowsum<<<dim3(16384), dim3(256), 0, stream>>>(adj, dsc);
  k_wconv<<<dim3(64), dim3(256), 0, stream>>>(W, Wb);
  k_xprep<<<dim3(32, 4, 8), dim3(256), 0, stream>>>(X, dsc, XpT);
  k_fused<<<dim3(256), dim3(512), 0, stream>>>(adj, XpT, X, dsc, Wb, bias, out);
}

// Round 3
// 89.829 us; speedup vs baseline: 1.0605x; 1.0605x over previous
//
#include <hip/hip_runtime.h>
#include <stdint.h>

typedef __attribute__((ext_vector_type(8))) short bf16x8;
typedef __attribute__((ext_vector_type(4))) float f32x4;
typedef unsigned short u16;

constexpr int NN = 2048, NF = 256;

__device__ inline u16 f2bf(float f) {
  uint32_t u = __builtin_bit_cast(uint32_t, f);
  uint32_t r = (u + 0x7FFFu + ((u >> 16) & 1u)) >> 16;
  return (u16)r;
}

__device__ inline void gload_lds16(const void* g, void* l) {
  __builtin_amdgcn_global_load_lds(
      (const __attribute__((address_space(1))) uint32_t*)g,
      (__attribute__((address_space(3))) uint32_t*)l,
      16, 0, 0);
}

// ---------------- K1: d[b,i] = rsqrt(1 + sum_j adj[b,i,j]) ----------------
__global__ __launch_bounds__(256) void k_rowsum(const float* __restrict__ adj,
                                                float* __restrict__ d) {
  int row = blockIdx.x;
  const float4* p = (const float4*)(adj + (size_t)row * NN);
  float s = 0.f;
#pragma unroll
  for (int c = 0; c < 2; ++c) {
    float4 v = p[threadIdx.x + 256 * c];
    s += v.x + v.y + v.z + v.w;
  }
#pragma unroll
  for (int off = 32; off > 0; off >>= 1) s += __shfl_down(s, off, 64);
  __shared__ float red[4];
  int lane = threadIdx.x & 63, w = threadIdx.x >> 6;
  if (lane == 0) red[w] = s;
  __syncthreads();
  if (threadIdx.x == 0) {
    float t = red[0] + red[1] + red[2] + red[3] + 1.0f;
    d[row] = 1.0f / sqrtf(t);
  }
}

// ---------------- Wconv: W fp32 -> bf16 ([o][f] kept) -----------------------
__global__ __launch_bounds__(256) void k_wconv(const float* __restrict__ W,
                                               u16* __restrict__ Wb) {
  int i = blockIdx.x * 256 + threadIdx.x;
  float4 v = ((const float4*)W)[i];
  ushort4 o;
  o.x = f2bf(v.x); o.y = f2bf(v.y); o.z = f2bf(v.z); o.w = f2bf(v.w);
  *(ushort4*)(Wb + (size_t)i * 4) = o;
}

// ---------------- K2: XpT[b,f,j'] = bf16(d_j * X[b,j,f]), j' XOR-swizzled ---
__global__ __launch_bounds__(256) void k_xprep(const float* __restrict__ X,
                                               const float* __restrict__ d,
                                               u16* __restrict__ XpT) {
  int jt = blockIdx.x, ft = blockIdx.y, b = blockIdx.z;
  int j0 = jt * 64, f0 = ft * 64;
  __shared__ u16 T[64][66];
  int t = threadIdx.x;
#pragma unroll
  for (int s = 0; s < 4; ++s) {
    int q = s * 256 + t;
    int r = q >> 4, c4 = q & 15;
    int j = j0 + r;
    float dv = d[b * NN + j];
    float4 v = *(const float4*)(X + ((size_t)(b * NN + j)) * NF + f0 + c4 * 4);
    T[r][c4 * 4 + 0] = f2bf(v.x * dv);
    T[r][c4 * 4 + 1] = f2bf(v.y * dv);
    T[r][c4 * 4 + 2] = f2bf(v.z * dv);
    T[r][c4 * 4 + 3] = f2bf(v.w * dv);
  }
  __syncthreads();
#pragma unroll
  for (int s = 0; s < 4; ++s) {
    int q = s * 256 + t;
    int fr = q >> 4, c4 = q & 15;
    int f = f0 + fr;
    int swz = (f >> 1) & 3;
    int joff = (c4 * 4) ^ (swz << 3);
    ushort4 o;
    o.x = T[c4 * 4 + 0][fr]; o.y = T[c4 * 4 + 1][fr];
    o.z = T[c4 * 4 + 2][fr]; o.w = T[c4 * 4 + 3][fr];
    *(ushort4*)(XpT + ((size_t)(b * NF + f)) * NN + j0 + joff) = o;
  }
}

// ---------------- Fused: H = d_i*(adj@Xp) + d_i^2*X ; out = relu(H@W^T + b) -
// BM=32, BN=256, BK=32, 256 threads (4 waves, 1x4), 512 blocks = 2/CU.
// Depth-1 dbuf, ONE __syncthreads per K-step.
__global__ __launch_bounds__(256, 2) void k_fused(
    const float* __restrict__ adj, const u16* __restrict__ XpT,
    const float* __restrict__ X, const float* __restrict__ dsc,
    const u16* __restrict__ Wb, const float* __restrict__ bias,
    float* __restrict__ out) {
  int flat = blockIdx.x;
  int b = flat & 7, mt = flat >> 3;  // batch->XCD affinity
  int i0 = mt * 32;

  __shared__ __align__(16) char smem[36864];
  // As[2]: 2KB each at 0/2048; Bs[2]: 16KB each at 4096/20480
  u16* Hs = (u16*)smem;  // aliased after K loop (needs 16.9KB)

  int t = threadIdx.x;
  int lane = t & 63, w = t >> 6;
  int l15 = lane & 15, l4 = lane >> 4;
  int wc = w;  // waves 1x4: each wave 32 rows x 64 cols

  const float* adjb = adj + ((size_t)b * NN + i0) * NN;
  const u16* XpTb = XpT + (size_t)b * NF * NN;

  // A staging map: thread t -> row ar (0..31), float4 col ac4 (0..7)
  int ar = t >> 3, ac4 = t & 7;
  const float* a_row = adjb + (size_t)ar * NN + ac4 * 4;
  int a_chunk = (ac4 >> 1) ^ ((ar >> 1) & 3);
  int a_wr_off = ar * 64 + a_chunk * 16 + (ac4 & 1) * 8;

  f32x4 acc[2][4] = {};

  // ---- prologue: A(0)->regs->As0, B(0)->Bs0 ----
  {
    float4 araw = *(const float4*)(a_row);
#pragma unroll
    for (int c = 0; c < 4; ++c) {
      int q = c * 256 + t;
      gload_lds16(XpTb + (size_t)(q >> 2) * NN + (q & 3) * 8,
                  smem + 4096 + (size_t)(c * 256 + w * 64) * 16);
    }
    ushort4 o;
    o.x = f2bf(araw.x); o.y = f2bf(araw.y);
    o.z = f2bf(araw.z); o.w = f2bf(araw.w);
    *(ushort4*)(smem + a_wr_off) = o;
  }
  __syncthreads();

  // ---- main loop: 64 K-steps, one barrier each ----
  for (int k = 0; k < 64; ++k) {
    char* Ac = smem + ((k & 1) << 11);
    char* An = smem + (((k & 1) ^ 1) << 11);
    char* Bc = smem + 4096 + ((k & 1) << 14);
    char* Bn = smem + 4096 + (((k & 1) ^ 1) << 14);

    bf16x8 af[2], bfr[4];
#pragma unroll
    for (int mi = 0; mi < 2; ++mi) {
      int r = mi * 16 + l15;
      af[mi] = *(const bf16x8*)(Ac + r * 64 + ((l4 ^ ((r >> 1) & 3)) << 4));
    }
#pragma unroll
    for (int ni = 0; ni < 4; ++ni) {
      int n = wc * 64 + ni * 16 + l15;
      bfr[ni] = *(const bf16x8*)(Bc + n * 64 + ((l4 ^ ((n >> 1) & 3)) << 4));
    }
    __builtin_amdgcn_sched_barrier(0);

    float4 araw2;
    if (k < 63) {  // prefetch k+1: A->regs, B->LDS[nxt]
      araw2 = *(const float4*)(a_row + (k + 1) * 32);
      int k2 = (k + 1) * 32;
#pragma unroll
      for (int c = 0; c < 4; ++c) {
        int q = c * 256 + t;
        gload_lds16(XpTb + (size_t)(q >> 2) * NN + k2 + (q & 3) * 8,
                    Bn + (size_t)(c * 256 + w * 64) * 16);
      }
    }
    __builtin_amdgcn_sched_barrier(0);

    __builtin_amdgcn_s_setprio(1);
#pragma unroll
    for (int mi = 0; mi < 2; ++mi)
#pragma unroll
      for (int ni = 0; ni < 4; ++ni)
        acc[mi][ni] = __builtin_amdgcn_mfma_f32_16x16x32_bf16(af[mi], bfr[ni],
                                                              acc[mi][ni], 0, 0, 0);
    __builtin_amdgcn_s_setprio(0);
    __builtin_amdgcn_sched_barrier(0);

    if (k < 63) {  // A(k+1) regs -> LDS[nxt] (compiler waits vmcnt for araw2)
      ushort4 o;
      o.x = f2bf(araw2.x); o.y = f2bf(araw2.y);
      o.z = f2bf(araw2.z); o.w = f2bf(araw2.w);
      *(ushort4*)(An + a_wr_off) = o;
    }
    __syncthreads();  // drains B(k+1) glds; As/Bs[nxt] ready
  }

  // ---- epilogue 1: H tile -> LDS bf16 [32][264] ----
  const float* db = dsc + b * NN;
  const float* Xb = X + ((size_t)b * NN + i0) * NF;
#pragma unroll
  for (int mi = 0; mi < 2; ++mi) {
#pragma unroll
    for (int qq = 0; qq < 4; ++qq) {
      int il = mi * 16 + l4 * 4 + qq;
      float dv = db[i0 + il];
      float dv2 = dv * dv;
#pragma unroll
      for (int ni = 0; ni < 4; ++ni) {
        int f = wc * 64 + ni * 16 + l15;
        float hv = dv * acc[mi][ni][qq] + dv2 * Xb[(size_t)il * NF + f];
        Hs[il * 264 + f] = f2bf(hv);
      }
    }
  }
  __syncthreads();

  // ---- epilogue 2: out = relu(H @ W^T + bias), W frags from L2 ----
  f32x4 acc2[2][4] = {};
#pragma unroll
  for (int kk = 0; kk < 256; kk += 32) {
    bf16x8 a2[2], b2[4];
#pragma unroll
    for (int mi = 0; mi < 2; ++mi) {
      int r = mi * 16 + l15;
      a2[mi] = *(const bf16x8*)&Hs[r * 264 + kk + l4 * 8];
    }
#pragma unroll
    for (int ni = 0; ni < 4; ++ni) {
      int o = wc * 64 + ni * 16 + l15;
      b2[ni] = *(const bf16x8*)&Wb[(size_t)o * 256 + kk + l4 * 8];
    }
#pragma unroll
    for (int mi = 0; mi < 2; ++mi)
#pragma unroll
      for (int ni = 0; ni < 4; ++ni)
        acc2[mi][ni] = __builtin_amdgcn_mfma_f32_16x16x32_bf16(a2[mi], b2[ni],
                                                               acc2[mi][ni], 0, 0, 0);
  }

  float* outb = out + ((size_t)b * NN + i0) * NF;
#pragma unroll
  for (int mi = 0; mi < 2; ++mi) {
#pragma unroll
    for (int qq = 0; qq < 4; ++qq) {
      int il = mi * 16 + l4 * 4 + qq;
#pragma unroll
      for (int ni = 0; ni < 4; ++ni) {
        int o = wc * 64 + ni * 16 + l15;
        float v = acc2[mi][ni][qq] + bias[o];
        outb[(size_t)il * NF + o] = fmaxf(v, 0.f);
      }
    }
  }
}

extern "C" void kernel_launch(void* const* d_in, const int* in_sizes, int n_in,
                              void* d_out, int out_size, void* d_ws, size_t ws_size,
                              hipStream_t stream) {
  const float* X    = (const float*)d_in[0];
  const float* adj  = (const float*)d_in[1];
  const float* W    = (const float*)d_in[2];
  const float* bias = (const float*)d_in[3];
  float* out = (float*)d_out;

  char* ws = (char*)d_ws;
  float* dsc = (float*)(ws);                 // 64 KB
  u16*   Wb  = (u16*)(ws + 65536);           // 128 KB
  u16*   XpT = (u16*)(ws + 262144);          // 8 MB

  k_rowsum<<<dim3(16384), dim3(256), 0, stream>>>(adj, dsc);
  k_wconv<<<dim3(64), dim3(256), 0, stream>>>(W, Wb);
  k_xprep<<<dim3(32, 4, 8), dim3(256), 0, stream>>>(X, dsc, XpT);
  k_fused<<<dim3(512), dim3(256), 0, stream>>>(adj, XpT, X, dsc, Wb, bias, out);
}

// Round 4
// 85.730 us; speedup vs baseline: 1.1112x; 1.0478x over previous
//
#include <hip/hip_runtime.h>
#include <stdint.h>

typedef __attribute__((ext_vector_type(8))) short bf16x8;
typedef __attribute__((ext_vector_type(4))) float f32x4;
typedef unsigned short u16;

constexpr int NN = 2048, NF = 256;

__device__ inline u16 f2bf(float f) {
  uint32_t u = __builtin_bit_cast(uint32_t, f);
  uint32_t r = (u + 0x7FFFu + ((u >> 16) & 1u)) >> 16;
  return (u16)r;
}
__device__ inline float bf2f(u16 h) {
  uint32_t u = ((uint32_t)h) << 16;
  return __builtin_bit_cast(float, u);
}

__device__ inline void gload_lds16(const void* g, void* l) {
  __builtin_amdgcn_global_load_lds(
      (const __attribute__((address_space(1))) uint32_t*)g,
      (__attribute__((address_space(3))) uint32_t*)l,
      16, 0, 0);
}

// ---- K1: d[row]=rsqrt(1+sum adj[row,:]); adjb=bf16(adj); tail blocks: Wconv
__global__ __launch_bounds__(256) void k_rowsum(const float* __restrict__ adj,
                                                u16* __restrict__ adjb,
                                                float* __restrict__ d,
                                                const float* __restrict__ W,
                                                u16* __restrict__ Wb) {
  if (blockIdx.x >= 16384) {  // W fp32 -> bf16 (64 blocks)
    int i = (blockIdx.x - 16384) * 256 + threadIdx.x;
    float4 v = ((const float4*)W)[i];
    ushort4 o;
    o.x = f2bf(v.x); o.y = f2bf(v.y); o.z = f2bf(v.z); o.w = f2bf(v.w);
    *(ushort4*)(Wb + (size_t)i * 4) = o;
    return;
  }
  int row = blockIdx.x;
  const float4* p = (const float4*)(adj + (size_t)row * NN);
  u16* ob = adjb + (size_t)row * NN;
  float s = 0.f;
#pragma unroll
  for (int c = 0; c < 2; ++c) {
    int idx = threadIdx.x + 256 * c;
    float4 v = p[idx];
    s += v.x + v.y + v.z + v.w;
    ushort4 o;
    o.x = f2bf(v.x); o.y = f2bf(v.y); o.z = f2bf(v.z); o.w = f2bf(v.w);
    *(ushort4*)(ob + (size_t)idx * 4) = o;
  }
#pragma unroll
  for (int off = 32; off > 0; off >>= 1) s += __shfl_down(s, off, 64);
  __shared__ float red[4];
  int lane = threadIdx.x & 63, w = threadIdx.x >> 6;
  if (lane == 0) red[w] = s;
  __syncthreads();
  if (threadIdx.x == 0) {
    float t = red[0] + red[1] + red[2] + red[3] + 1.0f;
    d[row] = 1.0f / sqrtf(t);
  }
}

// ---- K2: XpT[b,f,j'] = bf16(d_j*X[b,j,f]), j' = j ^ (((f>>1)&3)<<3) --------
__global__ __launch_bounds__(256) void k_xprep(const float* __restrict__ X,
                                               const float* __restrict__ d,
                                               u16* __restrict__ XpT) {
  int jt = blockIdx.x, ft = blockIdx.y, b = blockIdx.z;
  int j0 = jt * 64, f0 = ft * 64;
  __shared__ u16 T[64][66];
  int t = threadIdx.x;
#pragma unroll
  for (int s = 0; s < 4; ++s) {
    int q = s * 256 + t;
    int r = q >> 4, c4 = q & 15;
    int j = j0 + r;
    float dv = d[b * NN + j];
    float4 v = *(const float4*)(X + ((size_t)(b * NN + j)) * NF + f0 + c4 * 4);
    T[r][c4 * 4 + 0] = f2bf(v.x * dv);
    T[r][c4 * 4 + 1] = f2bf(v.y * dv);
    T[r][c4 * 4 + 2] = f2bf(v.z * dv);
    T[r][c4 * 4 + 3] = f2bf(v.w * dv);
  }
  __syncthreads();
#pragma unroll
  for (int s = 0; s < 4; ++s) {
    int q = s * 256 + t;
    int fr = q >> 4, c4 = q & 15;
    int f = f0 + fr;
    int swz = (f >> 1) & 3;
    int joff = (c4 * 4) ^ (swz << 3);
    ushort4 o;
    o.x = T[c4 * 4 + 0][fr]; o.y = T[c4 * 4 + 1][fr];
    o.z = T[c4 * 4 + 2][fr]; o.w = T[c4 * 4 + 3][fr];
    *(ushort4*)(XpT + ((size_t)(b * NF + f)) * NN + j0 + joff) = o;
  }
}

// ---- Fused: H = d_i*(adjb@Xp + Xp_i) ; out = relu(H@W^T + bias) ------------
// BM=32, BN=256, BK=32, 256 thr (4 waves 1x4), 512 blocks = 2/CU.
// All staging via gload_lds (A source pre-swizzled per-lane), 1 barrier/step.
__global__ __launch_bounds__(256, 2) void k_fused(
    const u16* __restrict__ adjb, const u16* __restrict__ XpT,
    const float* __restrict__ dsc, const u16* __restrict__ Wb,
    const float* __restrict__ bias, float* __restrict__ out) {
  int flat = blockIdx.x;
  int b = flat & 7, mt = flat >> 3;  // batch->XCD affinity
  int i0 = mt * 32;

  __shared__ __align__(16) char smem[36864];
  // As[2]: 2KB @ 0/2048; Bs[2]: 16KB @ 4096/20480
  u16* Hs = (u16*)smem;  // aliased after K loop (16.9 KB)

  int t = threadIdx.x;
  int lane = t & 63, w = t >> 6;
  int l15 = lane & 15, l4 = lane >> 4;
  int wc = w;

  const u16* adjbb = adjb + ((size_t)b * NN + i0) * NN;
  const u16* XpTb = XpT + (size_t)b * NF * NN;

  // A staging map (per wave, lanes 0..31): row rl, chunk c; src k pre-swizzled
  int rl = (w << 3) + ((lane & 31) >> 2);
  int asrc_off = ((lane & 3) ^ ((rl >> 1) & 3)) * 8;  // element offset in k
  const u16* a_src = adjbb + (size_t)rl * NN + asrc_off;

  f32x4 acc[2][4] = {};

  // ---- prologue: A(0)->As0, B(0)->Bs0 ----
  if (lane < 32) gload_lds16(a_src, smem + (w << 9));
#pragma unroll
  for (int c = 0; c < 4; ++c) {
    int q = c * 256 + t;
    gload_lds16(XpTb + (size_t)(q >> 2) * NN + (q & 3) * 8,
                smem + 4096 + (size_t)(c * 256 + w * 64) * 16);
  }
  __syncthreads();

  // ---- main loop: 64 K-steps, one barrier each ----
  for (int k = 0; k < 64; ++k) {
    char* Ac = smem + ((k & 1) << 11);
    char* An = smem + (((k & 1) ^ 1) << 11);
    char* Bc = smem + 4096 + ((k & 1) << 14);
    char* Bn = smem + 4096 + (((k & 1) ^ 1) << 14);

    bf16x8 af[2], bfr[4];
#pragma unroll
    for (int mi = 0; mi < 2; ++mi) {
      int r = mi * 16 + l15;
      af[mi] = *(const bf16x8*)(Ac + r * 64 + ((l4 ^ ((r >> 1) & 3)) << 4));
    }
#pragma unroll
    for (int ni = 0; ni < 4; ++ni) {
      int n = wc * 64 + ni * 16 + l15;
      bfr[ni] = *(const bf16x8*)(Bc + n * 64 + ((l4 ^ ((n >> 1) & 3)) << 4));
    }
    __builtin_amdgcn_sched_barrier(0);

    if (k < 63) {  // prefetch k+1 direct-to-LDS
      int k2 = (k + 1) * 32;
      if (lane < 32) gload_lds16(a_src + k2, An + (w << 9));
#pragma unroll
      for (int c = 0; c < 4; ++c) {
        int q = c * 256 + t;
        gload_lds16(XpTb + (size_t)(q >> 2) * NN + k2 + (q & 3) * 8,
                    Bn + (size_t)(c * 256 + w * 64) * 16);
      }
    }
    __builtin_amdgcn_sched_barrier(0);

    __builtin_amdgcn_s_setprio(1);
#pragma unroll
    for (int mi = 0; mi < 2; ++mi)
#pragma unroll
      for (int ni = 0; ni < 4; ++ni)
        acc[mi][ni] = __builtin_amdgcn_mfma_f32_16x16x32_bf16(af[mi], bfr[ni],
                                                              acc[mi][ni], 0, 0, 0);
    __builtin_amdgcn_s_setprio(0);
    __builtin_amdgcn_sched_barrier(0);
    __syncthreads();  // drains gloads; As/Bs[nxt] ready
  }

  // ---- epilogue 1: H tile -> LDS bf16 [32][264]; +I term from XpT (L2) ----
  const float* db = dsc + b * NN;
#pragma unroll
  for (int mi = 0; mi < 2; ++mi) {
#pragma unroll
    for (int ni = 0; ni < 4; ++ni) {
      int f = wc * 64 + ni * 16 + l15;
      int swz8 = ((f >> 1) & 3) << 3;
      ushort4 xv = *(const ushort4*)(XpTb + (size_t)f * NN + i0 +
                                     ((mi * 16 + l4 * 4) ^ swz8));
#pragma unroll
      for (int qq = 0; qq < 4; ++qq) {
        int il = mi * 16 + l4 * 4 + qq;
        float dv = db[i0 + il];
        float xpv = bf2f(((const u16*)&xv)[qq]);
        float hv = dv * (acc[mi][ni][qq] + xpv);
        Hs[il * 264 + f] = f2bf(hv);
      }
    }
  }
  __syncthreads();

  // ---- epilogue 2: out = relu(H @ W^T + bias), W frags from L2 ----
  f32x4 acc2[2][4] = {};
#pragma unroll
  for (int kk = 0; kk < 256; kk += 32) {
    bf16x8 a2[2], b2[4];
#pragma unroll
    for (int mi = 0; mi < 2; ++mi) {
      int r = mi * 16 + l15;
      a2[mi] = *(const bf16x8*)&Hs[r * 264 + kk + l4 * 8];
    }
#pragma unroll
    for (int ni = 0; ni < 4; ++ni) {
      int o = wc * 64 + ni * 16 + l15;
      b2[ni] = *(const bf16x8*)&Wb[(size_t)o * 256 + kk + l4 * 8];
    }
#pragma unroll
    for (int mi = 0; mi < 2; ++mi)
#pragma unroll
      for (int ni = 0; ni < 4; ++ni)
        acc2[mi][ni] = __builtin_amdgcn_mfma_f32_16x16x32_bf16(a2[mi], b2[ni],
                                                               acc2[mi][ni], 0, 0, 0);
  }

  float* outb = out + ((size_t)b * NN + i0) * NF;
#pragma unroll
  for (int mi = 0; mi < 2; ++mi) {
#pragma unroll
    for (int qq = 0; qq < 4; ++qq) {
      int il = mi * 16 + l4 * 4 + qq;
#pragma unroll
      for (int ni = 0; ni < 4; ++ni) {
        int o = wc * 64 + ni * 16 + l15;
        float v = acc2[mi][ni][qq] + bias[o];
        outb[(size_t)il * NF + o] = fmaxf(v, 0.f);
      }
    }
  }
}

extern "C" void kernel_launch(void* const* d_in, const int* in_sizes, int n_in,
                              void* d_out, int out_size, void* d_ws, size_t ws_size,
                              hipStream_t stream) {
  const float* X    = (const float*)d_in[0];
  const float* adj  = (const float*)d_in[1];
  const float* W    = (const float*)d_in[2];
  const float* bias = (const float*)d_in[3];
  float* out = (float*)d_out;

  char* ws = (char*)d_ws;
  float* dsc  = (float*)(ws);                          // 64 KB
  u16*   Wb   = (u16*)(ws + 65536);                    // 128 KB
  u16*   XpT  = (u16*)(ws + 262144);                   // 8 MB
  u16*   adjb = (u16*)(ws + 262144 + 8388608);         // 64 MB

  k_rowsum<<<dim3(16448), dim3(256), 0, stream>>>(adj, adjb, dsc, W, Wb);
  k_xprep<<<dim3(32, 4, 8), dim3(256), 0, stream>>>(X, dsc, XpT);
  k_fused<<<dim3(512), dim3(256), 0, stream>>>(adjb, XpT, dsc, Wb, bias, out);
}